// Round 10
// baseline (668.774 us; speedup 1.0000x reference)
//
#include <hip/hip_runtime.h>

#define NN 50000
#define NE 800000
#define NB 196   // (NN+255)/256

typedef unsigned int  u32;
typedef unsigned short u16;
typedef __attribute__((ext_vector_type(8))) short short8;
typedef __attribute__((ext_vector_type(4))) float f32x4;

union ABfrag { uint2 u2[2]; uint4 u4; short8 s8; };

__device__ __forceinline__ float silu_f(float v) {
    return v * __builtin_amdgcn_rcpf(1.0f + __expf(-v));
}
// cheap bf16 pair pack (round-half-up): 2 adds + 1 v_perm
__device__ __forceinline__ u32 pk2(float lo, float hi) {
    return __builtin_amdgcn_perm(__float_as_uint(hi) + 0x8000u,
                                 __float_as_uint(lo) + 0x8000u, 0x07060302u);
}
__device__ __forceinline__ float bff(u32 h) { return __uint_as_float(h << 16); }

// ---------------- embedding: h64 = h @ emb_w + emb_b  (N x 16 -> N x 64)
__global__ __launch_bounds__(256, 4) void k_embed(const float* __restrict__ h,
        const float* __restrict__ w, const float* __restrict__ b,
        float* __restrict__ h64) {
    int n = blockIdx.x * 256 + threadIdx.x;
    if (n >= NN) return;
    const float4* h4 = (const float4*)(h + (long)n * 16);
    float in[16];
    #pragma unroll
    for (int c = 0; c < 4; ++c) {
        float4 v = h4[c];
        in[4*c+0] = v.x; in[4*c+1] = v.y; in[4*c+2] = v.z; in[4*c+3] = v.w;
    }
    float acc[64];
    #pragma unroll
    for (int j = 0; j < 64; ++j) acc[j] = b[j];
    #pragma unroll
    for (int k = 0; k < 16; ++k) {
        #pragma unroll
        for (int j = 0; j < 64; ++j) acc[j] = fmaf(in[k], w[k*64 + j], acc[j]);
    }
    float4* o4 = (float4*)(h64 + (long)n * 64);
    #pragma unroll
    for (int c = 0; c < 16; ++c)
        o4[c] = make_float4(acc[4*c+0], acc[4*c+1], acc[4*c+2], acc[4*c+3]);
}

// ---------------- CSR-order build ----------------
__global__ __launch_bounds__(256, 4) void k_hist(const int* __restrict__ row,
        int* __restrict__ deg) {
    int e = blockIdx.x * 256 + threadIdx.x;
    if (e < NE) atomicAdd(&deg[row[e]], 1);
}

__global__ __launch_bounds__(256, 4) void k_scanA(const int* __restrict__ deg,
        int* __restrict__ bsum) {
    int t = threadIdx.x, i = blockIdx.x * 256 + t;
    int v = (i < NN) ? deg[i] : 0;
    #pragma unroll
    for (int d = 1; d < 64; d <<= 1) v += __shfl_xor(v, d);
    __shared__ int ws[4];
    if ((t & 63) == 0) ws[t >> 6] = v;
    __syncthreads();
    if (t == 0) bsum[blockIdx.x] = ws[0] + ws[1] + ws[2] + ws[3];
}

__global__ __launch_bounds__(256) void k_scanB(const int* __restrict__ bsum,
        int* __restrict__ bpre) {
    __shared__ int s[256];
    int t = threadIdx.x;
    int v = (t < NB) ? bsum[t] : 0;
    s[t] = v;
    __syncthreads();
    #pragma unroll
    for (int d = 1; d < 256; d <<= 1) {
        int u = (t >= d) ? s[t - d] : 0;
        __syncthreads();
        s[t] += u;
        __syncthreads();
    }
    if (t < NB) bpre[t] = s[t] - v;
}

__global__ __launch_bounds__(256, 4) void k_scanC(const int* __restrict__ deg,
        const int* __restrict__ bpre, int* __restrict__ base) {
    int t = threadIdx.x, i = blockIdx.x * 256 + t;
    int lane = t & 63, w = t >> 6;
    int v = (i < NN) ? deg[i] : 0;
    int x = v;
    #pragma unroll
    for (int d = 1; d < 64; d <<= 1) {
        int u = __shfl_up(x, d);
        if (lane >= d) x += u;
    }
    __shared__ int wsum[4];
    if (lane == 63) wsum[w] = x;
    __syncthreads();
    int off = bpre[blockIdx.x];
    #pragma unroll
    for (int ww = 0; ww < 3; ++ww) if (ww < w) off += wsum[ww];
    if (i < NN) base[i] = off + x - v;
}

__global__ __launch_bounds__(256, 4) void k_scatter(const int* __restrict__ row,
        const int* __restrict__ col, int* __restrict__ base,
        int* __restrict__ rowS, int* __restrict__ colS) {
    int e = blockIdx.x * 256 + threadIdx.x;
    if (e >= NE) return;
    int r = row[e];
    int p = atomicAdd(&base[r], 1);
    rowS[p] = r;
    colS[p] = col[e];
}

// ---------------- per-edge squared distance (sorted edge space)
__global__ __launch_bounds__(256, 4) void k_radial(const float* __restrict__ x,
        const int* __restrict__ rowS, const int* __restrict__ colS,
        float* __restrict__ radial) {
    int e = blockIdx.x * 256 + threadIdx.x;
    if (e >= NE) return;
    int r = rowS[e], c = colS[e];
    float dx = x[r*3+0] - x[c*3+0];
    float dy = x[r*3+1] - x[c*3+1];
    float dz = x[r*3+2] - x[c*3+2];
    radial[e] = dx*dx + dy*dy + dz*dz;
}

// ---------------- weight -> bf16 B-fragment tables (RNE, one-time)
__device__ __forceinline__ u32 bfr_rne(float x) {
    u32 u = __float_as_uint(x);
    u += 0x7fffu + ((u >> 16) & 1u);
    return u >> 16;
}
__global__ __launch_bounds__(256, 4) void k_wconv(const float* __restrict__ e_w2,
        const float* __restrict__ q_w2, const float* __restrict__ n_w1,
        const float* __restrict__ n_w2, const float* __restrict__ e_w1,
        const float* __restrict__ q_w1, u16* __restrict__ wf) {
    int t = blockIdx.x * 256 + threadIdx.x;
    if (t >= 122880) return;
    int j, lane, n, s, k, col;
    if (t < 24576) {
        int L = t >> 12, v = t & 4095;
        j = v & 7; lane = (v >> 3) & 63; int ns = v >> 9; n = ns >> 1; s = ns & 1;
        k = 8*(lane >> 4) + j + 32*s;
        col = 16*n + (lane & 15);
        const float* src = (L < 4) ? e_w2 + (size_t)L*4096 : q_w2 + (size_t)(L-4)*4096;
        wf[t] = (u16)bfr_rne(src[k*64 + col]);
    } else if (t < 57344) {
        int u = t - 24576; int L = u >> 13, v = u & 8191;
        j = v & 7; lane = (v >> 3) & 63; int ns = v >> 9; n = ns >> 2; s = ns & 3;
        k = 8*(lane >> 4) + j + 32*s;
        col = 16*n + (lane & 15);
        wf[t] = (u16)bfr_rne(n_w1[(size_t)L*8192 + k*64 + col]);
    } else if (t < 73728) {
        int u = t - 57344; int L = u >> 12, v = u & 4095;
        j = v & 7; lane = (v >> 3) & 63; int ns = v >> 9; n = ns >> 1; s = ns & 1;
        k = 8*(lane >> 4) + j + 32*s;
        col = 16*n + (lane & 15);
        wf[t] = (u16)bfr_rne(n_w2[(size_t)L*4096 + k*64 + col]);
    } else {
        int u = t - 73728;
        int L = u >> 13;
        int v = u & 8191;
        int m = v >> 12;
        int v2 = v & 4095;
        j = v2 & 7; lane = (v2 >> 3) & 63; int ns = v2 >> 9; n = ns >> 1; s = ns & 1;
        k = 8*(lane >> 4) + j + 32*s;
        col = 16*n + (lane & 15);
        const float* src = (L < 4) ? e_w1 + (size_t)L*130*64
                                   : q_w1 + (size_t)(L-4)*130*64;
        wf[t] = (u16)bfr_rne(src[(size_t)(m*64 + k)*64 + col]);
    }
}

// ---------------- standalone P/Q via MFMA (layers l0, l2 only)
__global__ __launch_bounds__(256, 4) void k_pq(const float* __restrict__ h64,
        const u16* __restrict__ wpf, const float* __restrict__ b1,
        u32* __restrict__ Pb, u32* __restrict__ Qb) {
    __shared__ u16 A[64*64];
    __shared__ u16 XP[64*68], XQ[64*68];
    int t = threadIdx.x, w = t >> 6, lane = t & 63;
    int nb0 = blockIdx.x * 64;
    #pragma unroll
    for (int i = 0; i < 4; ++i) {
        int idx = i*256 + t;
        int r = idx >> 4, c = idx & 15;
        int n = nb0 + r;
        float4 v = make_float4(0.f, 0.f, 0.f, 0.f);
        if (n < NN) v = ((const float4*)(h64 + (size_t)n*64))[c];
        uint2 pk = make_uint2(pk2(v.x, v.y), pk2(v.z, v.w));
        *(uint2*)((char*)A + r*128 + ((8*c) ^ ((r & 15) << 3))) = pk;
    }
    __syncthreads();
    int r0 = lane & 15, g = lane >> 4;
    ABfrag bp[2], bq[2];
    #pragma unroll
    for (int s = 0; s < 2; ++s) {
        bp[s].u4 = *(const uint4*)(wpf + ((size_t)(w*2 + s)*64 + lane)*8);
        bq[s].u4 = *(const uint4*)(wpf + 4096 + ((size_t)(w*2 + s)*64 + lane)*8);
    }
    f32x4 aP[4], aQ[4];
    #pragma unroll
    for (int t4 = 0; t4 < 4; ++t4) {
        aP[t4] = (f32x4){0.f, 0.f, 0.f, 0.f};
        aQ[t4] = (f32x4){0.f, 0.f, 0.f, 0.f};
    }
    #pragma unroll
    for (int t4 = 0; t4 < 4; ++t4) {
        #pragma unroll
        for (int s = 0; s < 2; ++s) {
            int boff = 16*g + 64*s;
            ABfrag af;
            af.u2[0] = *(uint2*)((char*)A + (16*t4 + r0)*128 + ( boff      ^ (r0 << 3)));
            af.u2[1] = *(uint2*)((char*)A + (16*t4 + r0)*128 + ((boff + 8) ^ (r0 << 3)));
            aP[t4] = __builtin_amdgcn_mfma_f32_16x16x32_bf16(af.s8, bp[s].s8, aP[t4], 0, 0, 0);
            aQ[t4] = __builtin_amdgcn_mfma_f32_16x16x32_bf16(af.s8, bq[s].s8, aQ[t4], 0, 0, 0);
        }
    }
    float bv = b1[16*w + r0];
    #pragma unroll
    for (int t4 = 0; t4 < 4; ++t4)
        #pragma unroll
        for (int q = 0; q < 4; ++q) {
            int rw = 16*t4 + 4*g + q;
            XP[rw*68 + 16*w + r0] = (u16)(pk2(aP[t4][q] + bv, 0.f) & 0xffffu);
            XQ[rw*68 + 16*w + r0] = (u16)(pk2(aQ[t4][q], 0.f) & 0xffffu);
        }
    __syncthreads();
    int node = t >> 2, part = t & 3;
    if (nb0 + node < NN) {
        const u32* XPw = (const u32*)XP;
        const u32* XQw = (const u32*)XQ;
        u32 b[8];
        #pragma unroll
        for (int j = 0; j < 8; ++j) b[j] = XPw[node*34 + 8*part + j];
        uint4* dp = (uint4*)(Pb + (size_t)(nb0 + node)*32 + part*8);
        dp[0] = make_uint4(b[0], b[1], b[2], b[3]);
        dp[1] = make_uint4(b[4], b[5], b[6], b[7]);
        #pragma unroll
        for (int j = 0; j < 8; ++j) b[j] = XQw[node*34 + 8*part + j];
        uint4* dq = (uint4*)(Qb + (size_t)(nb0 + node)*32 + part*8);
        dq[0] = make_uint4(b[0], b[1], b[2], b[3]);
        dq[1] = make_uint4(b[4], b[5], b[6], b[7]);
    }
}

// ---------------- edge MLP: reg-direct A-fragments, no barriers, M in LDS
__global__ __launch_bounds__(256, 4) void k_edge(
        const u32* __restrict__ Pb, const u32* __restrict__ Qb,
        const float* __restrict__ radial, const float* __restrict__ dist0,
        const int* __restrict__ rowS, const int* __restrict__ colS,
        const float* __restrict__ w1t, const u16* __restrict__ w2f,
        const float* __restrict__ b2, float* __restrict__ agg) {
    __shared__ u16 M_lds[4][64*66];   // per-wave [64 feat][66 edge] bf16
    int tid = threadIdx.x;
    int w = tid >> 6, lane = tid & 63;
    int ebase = blockIdx.x * 256 + w * 64;
    u16* Mw = M_lds[w];
    int r0 = lane & 15, g = lane >> 4;
    // lane's k-slices: s=0 -> k in [8g,8g+8), s=1 -> k in [32+8g, 32+8g+8)
    float wa[16], wb[16];
    *(float4*)&wa[0]  = *(const float4*)(w1t + 8*g);
    *(float4*)&wa[4]  = *(const float4*)(w1t + 8*g + 4);
    *(float4*)&wa[8]  = *(const float4*)(w1t + 32 + 8*g);
    *(float4*)&wa[12] = *(const float4*)(w1t + 36 + 8*g);
    *(float4*)&wb[0]  = *(const float4*)(w1t + 64 + 8*g);
    *(float4*)&wb[4]  = *(const float4*)(w1t + 68 + 8*g);
    *(float4*)&wb[8]  = *(const float4*)(w1t + 96 + 8*g);
    *(float4*)&wb[12] = *(const float4*)(w1t + 100 + 8*g);
    ABfrag bf[4][2];
    #pragma unroll
    for (int n = 0; n < 4; ++n)
        #pragma unroll
        for (int s = 0; s < 2; ++s)
            bf[n][s].u4 = *(const uint4*)(w2f + ((n*2 + s)*64 + lane)*8);
    float b2v[4];
    #pragma unroll
    for (int n = 0; n < 4; ++n) b2v[n] = b2[16*n + r0];
    #pragma unroll
    for (int t = 0; t < 4; ++t) {
        int et = ebase + 16*t + r0;        // edge this lane's A-row serves
        int r = rowS[et], c = colS[et];
        float rad = radial[et], d0 = dist0[et];
        uint4 pA = *(const uint4*)(Pb + (size_t)r*32 + 4*g);
        uint4 pB = *(const uint4*)(Pb + (size_t)r*32 + 16 + 4*g);
        uint4 qA = *(const uint4*)(Qb + (size_t)c*32 + 4*g);
        uint4 qB = *(const uint4*)(Qb + (size_t)c*32 + 16 + 4*g);
        u32 pu[8] = {pA.x, pA.y, pA.z, pA.w, pB.x, pB.y, pB.z, pB.w};
        u32 qu[8] = {qA.x, qA.y, qA.z, qA.w, qB.x, qB.y, qB.z, qB.w};
        u32 pk[8];
        #pragma unroll
        for (int i = 0; i < 8; ++i) {
            int kb = (i >> 2) * 8 + (i & 3) * 2;
            float pl = bff(pu[i] & 0xffffu), ph = bff(pu[i] >> 16);
            float ql = bff(qu[i] & 0xffffu), qh = bff(qu[i] >> 16);
            float h0 = silu_f(pl + ql + rad*wa[kb]   + d0*wb[kb]);
            float h1 = silu_f(ph + qh + rad*wa[kb+1] + d0*wb[kb+1]);
            pk[i] = pk2(h0, h1);
        }
        ABfrag af0, af1;
        af0.u4 = make_uint4(pk[0], pk[1], pk[2], pk[3]);
        af1.u4 = make_uint4(pk[4], pk[5], pk[6], pk[7]);
        f32x4 acc[4];
        #pragma unroll
        for (int n = 0; n < 4; ++n) acc[n] = (f32x4){0.f, 0.f, 0.f, 0.f};
        #pragma unroll
        for (int n = 0; n < 4; ++n) {
            acc[n] = __builtin_amdgcn_mfma_f32_16x16x32_bf16(af0.s8, bf[n][0].s8, acc[n], 0, 0, 0);
            acc[n] = __builtin_amdgcn_mfma_f32_16x16x32_bf16(af1.s8, bf[n][1].s8, acc[n], 0, 0, 0);
        }
        // epilogue: lane holds feature 16n+r0, edges 16t+4g+q
        #pragma unroll
        for (int n = 0; n < 4; ++n) {
            f32x4 z = acc[n];
            u32 m0 = pk2(silu_f(z[0] + b2v[n]), silu_f(z[1] + b2v[n]));
            u32 m1 = pk2(silu_f(z[2] + b2v[n]), silu_f(z[3] + b2v[n]));
            *(uint2*)((char*)Mw + (16*n + r0)*132 + 32*t + 8*g) = make_uint2(m0, m1);
        }
    }
    // aggregation: per-wave LDS, DS pipe is in-order within a wave -> no barrier
    int rl = rowS[ebase + lane];
    int rnext = __shfl_down(rl, 1);
    unsigned long long tm = __ballot((lane == 63) || (rnext != rl));
    float racc = 0.0f;
    #pragma unroll
    for (int ch = 0; ch < 16; ++ch) {
        uint2 mm = *(uint2*)((char*)Mw + lane*132 + 8*ch);
        u32 mw[2] = {mm.x, mm.y};
        #pragma unroll
        for (int q = 0; q < 4; ++q) {
            int ee = 4*ch + q;
            racc += bff((mw[q >> 1] >> ((q & 1) * 16)) & 0xffffu);
            if ((tm >> ee) & 1ull) {
                int rr = __builtin_amdgcn_readlane(rl, ee);
                atomicAdd(&agg[(size_t)rr*64 + lane], racc);
                racc = 0.0f;
            }
        }
    }
}

// ---------------- fused node MLP + next-layer P/Q (all MFMA)
__global__ __launch_bounds__(256, 3) void k_node_pq(float* __restrict__ h64,
        const float* __restrict__ agg,
        const u16* __restrict__ w1f, const float* __restrict__ b1,
        const u16* __restrict__ w2f, const float* __restrict__ b2,
        const u16* __restrict__ wpf, const float* __restrict__ b1pq,
        u32* __restrict__ Pb, u32* __restrict__ Qb) {
    __shared__ u16 S[16512];
    u16* A0 = S;
    u16* A1 = S + 4096;
    u16* H  = S + 8192;
    u16* D  = S + 12288;
    u16* An = S;
    u16* XPh = S + 4096;
    u16* XQh = S + 8448;
    int t = threadIdx.x, w = t >> 6, lane = t & 63;
    int nb0 = blockIdx.x * 64;
    #pragma unroll
    for (int i = 0; i < 8; ++i) {
        int idx = i*256 + t;
        int r = idx >> 5, c = idx & 31;
        int n = nb0 + r;
        float4 v = make_float4(0.f, 0.f, 0.f, 0.f);
        if (n < NN) {
            if (c < 16) v = ((const float4*)(h64 + (size_t)n*64))[c];
            else {
                float4 a = ((const float4*)(agg + (size_t)n*64))[c-16];
                v = make_float4(a.x*0.01f, a.y*0.01f, a.z*0.01f, a.w*0.01f);
            }
        }
        uint2 pk = make_uint2(pk2(v.x, v.y), pk2(v.z, v.w));
        u16* dst = (c < 16) ? A0 : A1;
        int cc = c & 15;
        *(uint2*)((char*)dst + r*128 + ((8*cc) ^ ((r & 15) << 3))) = pk;
    }
    __syncthreads();
    int r0 = lane & 15, g = lane >> 4;
    ABfrag bf1[4];
    #pragma unroll
    for (int s = 0; s < 4; ++s)
        bf1[s].u4 = *(const uint4*)(w1f + ((size_t)(w*4 + s)*64 + lane)*8);
    f32x4 acc[4];
    #pragma unroll
    for (int t4 = 0; t4 < 4; ++t4) acc[t4] = (f32x4){0.f, 0.f, 0.f, 0.f};
    #pragma unroll
    for (int t4 = 0; t4 < 4; ++t4) {
        #pragma unroll
        for (int s = 0; s < 4; ++s) {
            const u16* Ah = (s < 2) ? A0 : A1;
            int boff = 16*g + 64*(s & 1);
            ABfrag af;
            af.u2[0] = *(uint2*)((char*)Ah + (16*t4 + r0)*128 + ( boff      ^ (r0 << 3)));
            af.u2[1] = *(uint2*)((char*)Ah + (16*t4 + r0)*128 + ((boff + 8) ^ (r0 << 3)));
            acc[t4] = __builtin_amdgcn_mfma_f32_16x16x32_bf16(
                af.s8, bf1[s].s8, acc[t4], 0, 0, 0);
        }
    }
    float b1v = b1[16*w + r0];
    #pragma unroll
    for (int t4 = 0; t4 < 4; ++t4)
        #pragma unroll
        for (int q = 0; q < 4; ++q) {
            int rw = 16*t4 + 4*g + q;
            u16 hv = (u16)(pk2(silu_f(acc[t4][q] + b1v), 0.f) & 0xffffu);
            *(u16*)((char*)H + rw*128 + ((2*(16*w + r0)) ^ ((rw & 15) << 3))) = hv;
        }
    __syncthreads();
    ABfrag bf2[2];
    #pragma unroll
    for (int s = 0; s < 2; ++s)
        bf2[s].u4 = *(const uint4*)(w2f + ((size_t)(w*2 + s)*64 + lane)*8);
    f32x4 acc2[4];
    #pragma unroll
    for (int t4 = 0; t4 < 4; ++t4) acc2[t4] = (f32x4){0.f, 0.f, 0.f, 0.f};
    #pragma unroll
    for (int t4 = 0; t4 < 4; ++t4) {
        #pragma unroll
        for (int s = 0; s < 2; ++s) {
            int boff = 16*g + 64*s;
            ABfrag af;
            af.u2[0] = *(uint2*)((char*)H + (16*t4 + r0)*128 + ( boff      ^ (r0 << 3)));
            af.u2[1] = *(uint2*)((char*)H + (16*t4 + r0)*128 + ((boff + 8) ^ (r0 << 3)));
            acc2[t4] = __builtin_amdgcn_mfma_f32_16x16x32_bf16(
                af.s8, bf2[s].s8, acc2[t4], 0, 0, 0);
        }
    }
    float b2v = b2[16*w + r0];
    #pragma unroll
    for (int t4 = 0; t4 < 4; ++t4)
        #pragma unroll
        for (int q = 0; q < 4; ++q) {
            int rw = 16*t4 + 4*g + q;
            D[rw*66 + 16*w + r0] = (u16)(pk2(acc2[t4][q] + b2v, 0.f) & 0xffffu);
        }
    __syncthreads();
    #pragma unroll
    for (int i = 0; i < 4; ++i) {
        int idx = i*256 + t;
        int rr = idx >> 4, cc = idx & 15;
        int n = nb0 + rr;
        float4 v = make_float4(0.f, 0.f, 0.f, 0.f);
        if (n < NN) {
            v = ((const float4*)(h64 + (size_t)n*64))[cc];
            v.x += bff(D[rr*66 + 4*cc + 0]);
            v.y += bff(D[rr*66 + 4*cc + 1]);
            v.z += bff(D[rr*66 + 4*cc + 2]);
            v.w += bff(D[rr*66 + 4*cc + 3]);
            ((float4*)(h64 + (size_t)n*64))[cc] = v;
        }
        uint2 pk = make_uint2(pk2(v.x, v.y), pk2(v.z, v.w));
        *(uint2*)((char*)An + rr*128 + ((8*cc) ^ ((rr & 15) << 3))) = pk;
    }
    __syncthreads();
    ABfrag bp[2], bq[2];
    #pragma unroll
    for (int s = 0; s < 2; ++s) {
        bp[s].u4 = *(const uint4*)(wpf + ((size_t)(w*2 + s)*64 + lane)*8);
        bq[s].u4 = *(const uint4*)(wpf + 4096 + ((size_t)(w*2 + s)*64 + lane)*8);
    }
    f32x4 aP[4], aQ[4];
    #pragma unroll
    for (int t4 = 0; t4 < 4; ++t4) {
        aP[t4] = (f32x4){0.f, 0.f, 0.f, 0.f};
        aQ[t4] = (f32x4){0.f, 0.f, 0.f, 0.f};
    }
    #pragma unroll
    for (int t4 = 0; t4 < 4; ++t4) {
        #pragma unroll
        for (int s = 0; s < 2; ++s) {
            int boff = 16*g + 64*s;
            ABfrag af;
            af.u2[0] = *(uint2*)((char*)An + (16*t4 + r0)*128 + ( boff      ^ (r0 << 3)));
            af.u2[1] = *(uint2*)((char*)An + (16*t4 + r0)*128 + ((boff + 8) ^ (r0 << 3)));
            aP[t4] = __builtin_amdgcn_mfma_f32_16x16x32_bf16(af.s8, bp[s].s8, aP[t4], 0, 0, 0);
            aQ[t4] = __builtin_amdgcn_mfma_f32_16x16x32_bf16(af.s8, bq[s].s8, aQ[t4], 0, 0, 0);
        }
    }
    float bv = b1pq[16*w + r0];
    #pragma unroll
    for (int t4 = 0; t4 < 4; ++t4)
        #pragma unroll
        for (int q = 0; q < 4; ++q) {
            int rw = 16*t4 + 4*g + q;
            XPh[rw*68 + 16*w + r0] = (u16)(pk2(aP[t4][q] + bv, 0.f) & 0xffffu);
            XQh[rw*68 + 16*w + r0] = (u16)(pk2(aQ[t4][q], 0.f) & 0xffffu);
        }
    __syncthreads();
    int node = t >> 2, part = t & 3;
    if (nb0 + node < NN) {
        const u32* XPw = (const u32*)XPh;
        const u32* XQw = (const u32*)XQh;
        u32 b[8];
        #pragma unroll
        for (int j = 0; j < 8; ++j) b[j] = XPw[node*34 + 8*part + j];
        uint4* dp = (uint4*)(Pb + (size_t)(nb0 + node)*32 + part*8);
        dp[0] = make_uint4(b[0], b[1], b[2], b[3]);
        dp[1] = make_uint4(b[4], b[5], b[6], b[7]);
        #pragma unroll
        for (int j = 0; j < 8; ++j) b[j] = XQw[node*34 + 8*part + j];
        uint4* dq = (uint4*)(Qb + (size_t)(nb0 + node)*32 + part*8);
        dq[0] = make_uint4(b[0], b[1], b[2], b[3]);
        dq[1] = make_uint4(b[4], b[5], b[6], b[7]);
    }
}

// ---------------- coordinate update: reg-direct A, no barriers, tiny LDS
__global__ __launch_bounds__(256, 4) void k_coord(
        const u32* __restrict__ Pb, const u32* __restrict__ Qb,
        const float* __restrict__ radial, const float* __restrict__ dist0,
        const int* __restrict__ rowS, const int* __restrict__ colS,
        const float* __restrict__ w1t, const u16* __restrict__ w2f,
        const float* __restrict__ b2, const float* __restrict__ w3,
        const float* __restrict__ x_old, float* __restrict__ x_new) {
    __shared__ float PHL[4][64];
    int tid = threadIdx.x;
    int w = tid >> 6, lane = tid & 63;
    int ebase = blockIdx.x * 256 + w * 64;
    int r0 = lane & 15, g = lane >> 4;
    float wa[16], wb[16];
    *(float4*)&wa[0]  = *(const float4*)(w1t + 8*g);
    *(float4*)&wa[4]  = *(const float4*)(w1t + 8*g + 4);
    *(float4*)&wa[8]  = *(const float4*)(w1t + 32 + 8*g);
    *(float4*)&wa[12] = *(const float4*)(w1t + 36 + 8*g);
    *(float4*)&wb[0]  = *(const float4*)(w1t + 64 + 8*g);
    *(float4*)&wb[4]  = *(const float4*)(w1t + 68 + 8*g);
    *(float4*)&wb[8]  = *(const float4*)(w1t + 96 + 8*g);
    *(float4*)&wb[12] = *(const float4*)(w1t + 100 + 8*g);
    ABfrag bf[4][2];
    #pragma unroll
    for (int n = 0; n < 4; ++n)
        #pragma unroll
        for (int s = 0; s < 2; ++s)
            bf[n][s].u4 = *(const uint4*)(w2f + ((n*2 + s)*64 + lane)*8);
    float w3v[4], b2v[4];
    #pragma unroll
    for (int n = 0; n < 4; ++n) { w3v[n] = w3[16*n + r0]; b2v[n] = b2[16*n + r0]; }
    float ph[16];
    #pragma unroll
    for (int t = 0; t < 4; ++t) {
        int et = ebase + 16*t + r0;
        int r = rowS[et], c = colS[et];
        float rad = radial[et], d0 = dist0[et];
        uint4 pA = *(const uint4*)(Pb + (size_t)r*32 + 4*g);
        uint4 pB = *(const uint4*)(Pb + (size_t)r*32 + 16 + 4*g);
        uint4 qA = *(const uint4*)(Qb + (size_t)c*32 + 4*g);
        uint4 qB = *(const uint4*)(Qb + (size_t)c*32 + 16 + 4*g);
        u32 pu[8] = {pA.x, pA.y, pA.z, pA.w, pB.x, pB.y, pB.z, pB.w};
        u32 qu[8] = {qA.x, qA.y, qA.z, qA.w, qB.x, qB.y, qB.z, qB.w};
        u32 pk[8];
        #pragma unroll
        for (int i = 0; i < 8; ++i) {
            int kb = (i >> 2) * 8 + (i & 3) * 2;
            float pl = bff(pu[i] & 0xffffu), phh = bff(pu[i] >> 16);
            float ql = bff(qu[i] & 0xffffu), qh = bff(qu[i] >> 16);
            float h0 = silu_f(pl + ql + rad*wa[kb]   + d0*wb[kb]);
            float h1 = silu_f(phh + qh + rad*wa[kb+1] + d0*wb[kb+1]);
            pk[i] = pk2(h0, h1);
        }
        ABfrag af0, af1;
        af0.u4 = make_uint4(pk[0], pk[1], pk[2], pk[3]);
        af1.u4 = make_uint4(pk[4], pk[5], pk[6], pk[7]);
        f32x4 acc[4];
        #pragma unroll
        for (int n = 0; n < 4; ++n) acc[n] = (f32x4){0.f, 0.f, 0.f, 0.f};
        #pragma unroll
        for (int n = 0; n < 4; ++n) {
            acc[n] = __builtin_amdgcn_mfma_f32_16x16x32_bf16(af0.s8, bf[n][0].s8, acc[n], 0, 0, 0);
            acc[n] = __builtin_amdgcn_mfma_f32_16x16x32_bf16(af1.s8, bf[n][1].s8, acc[n], 0, 0, 0);
        }
        #pragma unroll
        for (int q = 0; q < 4; ++q) {
            float s = 0.f;
            #pragma unroll
            for (int n = 0; n < 4; ++n)
                s = fmaf(silu_f(acc[n][q] + b2v[n]), w3v[n], s);
            ph[t*4 + q] = s;
        }
    }
    // reduce phi over the 16-lane feature groups (r0 axis)
    #pragma unroll
    for (int d = 1; d < 16; d <<= 1)
        #pragma unroll
        for (int i = 0; i < 16; ++i) ph[i] += __shfl_xor(ph[i], d);
    if (r0 == 0) {
        #pragma unroll
        for (int t = 0; t < 4; ++t)
            #pragma unroll
            for (int q = 0; q < 4; ++q)
                PHL[w][16*t + 4*g + q] = ph[t*4 + q];
    }
    // per-wave LDS, within-wave in-order DS -> no barrier needed
    int e = ebase + lane;
    float phi = PHL[w][lane] * 0.01f;
    int r = rowS[e], c = colS[e];
    float rad = radial[e];
    float dx = x_old[r*3+0] - x_old[c*3+0];
    float dy = x_old[r*3+1] - x_old[c*3+1];
    float dz = x_old[r*3+2] - x_old[c*3+2];
    float inv = phi / (sqrtf(rad + 1e-8f) + 1.0f);
    float tx = dx * inv, ty = dy * inv, tz = dz * inv;
    int rprev = __shfl_up(r, 1);
    bool head = (lane == 0) || (rprev != r);
    unsigned long long hm = __ballot(head);
    int runid = __popcll(hm & ((2ull << lane) - 1ull));
    #pragma unroll
    for (int d = 1; d < 64; d <<= 1) {
        float ox = __shfl_up(tx, d);
        float oy = __shfl_up(ty, d);
        float oz = __shfl_up(tz, d);
        int orid = __shfl_up(runid, d);
        if (lane >= d && orid == runid) { tx += ox; ty += oy; tz += oz; }
    }
    int rid_next = __shfl_down(runid, 1);
    bool tail = (lane == 63) || (rid_next != runid);
    if (tail) {
        atomicAdd(&x_new[r*3+0], tx);
        atomicAdd(&x_new[r*3+1], ty);
        atomicAdd(&x_new[r*3+2], tz);
    }
}

// ---------------- output projection
__global__ __launch_bounds__(256, 4) void k_out(const float* __restrict__ h64,
        const float* __restrict__ w, const float* __restrict__ b,
        float* __restrict__ out) {
    int n = blockIdx.x * 256 + threadIdx.x;
    if (n >= NN) return;
    float acc[16];
    #pragma unroll
    for (int j = 0; j < 16; ++j) acc[j] = b[j];
    const float4* h4 = (const float4*)(h64 + (long)n*64);
    #pragma unroll
    for (int c = 0; c < 16; ++c) {
        float4 v = h4[c];
        float vv[4] = {v.x, v.y, v.z, v.w};
        #pragma unroll
        for (int t = 0; t < 4; ++t) {
            #pragma unroll
            for (int j = 0; j < 16; ++j)
                acc[j] = fmaf(vv[t], w[(4*c+t)*16 + j], acc[j]);
        }
    }
    float4* o4 = (float4*)(out + (long)n*16);
    #pragma unroll
    for (int cq = 0; cq < 4; ++cq)
        o4[cq] = make_float4(acc[4*cq+0],acc[4*cq+1],acc[4*cq+2],acc[4*cq+3]);
}

extern "C" void kernel_launch(void* const* d_in, const int* in_sizes, int n_in,
                              void* d_out, int out_size, void* d_ws, size_t ws_size,
                              hipStream_t stream) {
    const float* h_in  = (const float*)d_in[0];
    const float* x_in  = (const float*)d_in[1];
    const int*   row   = (const int*)d_in[2];
    const int*   col   = (const int*)d_in[3];
    const float* emb_w = (const float*)d_in[4];
    const float* emb_b = (const float*)d_in[5];
    const float* out_w = (const float*)d_in[6];
    const float* out_b = (const float*)d_in[7];
    const float* e_w1  = (const float*)d_in[8];
    const float* e_b1  = (const float*)d_in[9];
    const float* e_w2  = (const float*)d_in[10];
    const float* e_b2  = (const float*)d_in[11];
    const float* n_w1  = (const float*)d_in[12];
    const float* n_b1  = (const float*)d_in[13];
    const float* n_w2  = (const float*)d_in[14];
    const float* n_b2  = (const float*)d_in[15];
    const float* q_w1  = (const float*)d_in[16];
    const float* q_b1  = (const float*)d_in[17];
    const float* q_w2  = (const float*)d_in[18];
    const float* q_b2  = (const float*)d_in[19];
    const float* q_w3  = (const float*)d_in[20];

    const size_t WF_N = 122880;
    const size_t WF_BYTES = WF_N * sizeof(u16);
    size_t need = WF_BYTES + ((size_t)NN*64*4 + (size_t)NE*2 + (size_t)NN*3
                   + (size_t)NE*2 + (size_t)NN*2 + 1024) * sizeof(float);
    if (ws_size < need) return;

    u16*   wf    = (u16*)d_ws;
    float* fb    = (float*)((char*)d_ws + WF_BYTES);
    float* h64   = fb;
    u32*   Pb    = (u32*)(h64 + (size_t)NN*64);
    u32*   Qb    = Pb + (size_t)NN*32;
    float* agg   = (float*)(Qb + (size_t)NN*32);
    float* d0S   = agg   + (size_t)NN*64;
    float* radS  = d0S   + (size_t)NE;
    float* xA    = radS  + (size_t)NE;
    int*   rowS  = (int*)(xA + (size_t)NN*3);
    int*   colS  = rowS  + (size_t)NE;
    int*   deg   = colS  + (size_t)NE;
    int*   base  = deg   + (size_t)NN;
    int*   bsum  = base  + (size_t)NN;
    int*   bpre  = bsum  + 256;

    float* out_h = (float*)d_out;
    float* out_x = out_h + (size_t)NN*16;

    dim3 th(256);
    dim3 nb((NN + 255)/256);
    dim3 eb(NE/256);
    dim3 t64b((NN + 63)/64);

    hipMemsetAsync(deg, 0, (size_t)NN*sizeof(int), stream);
    k_hist<<<eb, th, 0, stream>>>(row, deg);
    k_scanA<<<NB, th, 0, stream>>>(deg, bsum);
    k_scanB<<<1, th, 0, stream>>>(bsum, bpre);
    k_scanC<<<NB, th, 0, stream>>>(deg, bpre, base);
    k_scatter<<<eb, th, 0, stream>>>(row, col, base, rowS, colS);
    k_wconv<<<480, th, 0, stream>>>(e_w2, q_w2, n_w1, n_w2, e_w1, q_w1, wf);

    k_radial<<<eb, th, 0, stream>>>(x_in, rowS, colS, d0S);
    k_embed<<<nb, th, 0, stream>>>(h_in, emb_w, emb_b, h64);

    const u16* nw1f = wf + 24576;
    const u16* nw2f = wf + 57344;
    const u16* pqf  = wf + 73728;

    for (int b = 0; b < 2; ++b) {
        const float* x_old;
        float*       x_new;
        const float* radp;
        if (b == 0) {
            x_old = x_in;  x_new = xA;    radp = d0S;
        } else {
            x_old = xA;    x_new = out_x; radp = radS;
            k_radial<<<eb, th, 0, stream>>>(x_old, rowS, colS, radS);
        }
        for (int i = 0; i < 2; ++i) {
            int l = b*2 + i;
            if (i == 0)
                k_pq<<<t64b, th, 0, stream>>>(h64, pqf + (size_t)l*8192,
                                              e_b1 + (size_t)l*64, Pb, Qb);
            hipMemsetAsync(agg, 0, (size_t)NN*64*sizeof(float), stream);
            k_edge<<<eb, th, 0, stream>>>(Pb, Qb, radp, d0S, rowS, colS,
                    e_w1 + (size_t)l*130*64 + 128*64,
                    wf + (size_t)l*4096,
                    e_b2 + (size_t)l*64, agg);
            const u16* nxt_f  = (i == 0) ? pqf + (size_t)(l+1)*8192
                                         : pqf + (size_t)(4 + b)*8192;
            const float* nxt_b = (i == 0) ? e_b1 + (size_t)(l+1)*64
                                          : q_b1 + (size_t)b*64;
            k_node_pq<<<t64b, th, 0, stream>>>(h64, agg,
                    nw1f + (size_t)l*8192, n_b1 + (size_t)l*64,
                    nw2f + (size_t)l*4096, n_b2 + (size_t)l*64,
                    nxt_f, nxt_b, Pb, Qb);
        }
        hipMemcpyAsync(x_new, x_old, (size_t)NN*3*sizeof(float),
                       hipMemcpyDeviceToDevice, stream);
        k_coord<<<eb, th, 0, stream>>>(Pb, Qb, radp, d0S, rowS, colS,
                q_w1 + (size_t)b*130*64 + 128*64,
                wf + (size_t)(4 + b)*4096,
                q_b2 + (size_t)b*64, q_w3 + (size_t)b*64, x_old, x_new);
    }
    k_out<<<nb, th, 0, stream>>>(h64, out_w, out_b, out_h);
}

// Round 11
// 668.007 us; speedup vs baseline: 1.0011x; 1.0011x over previous
//
#include <hip/hip_runtime.h>

#define NN 50000
#define NE 800000
#define NB 196   // (NN+255)/256

typedef unsigned int  u32;
typedef unsigned short u16;
typedef __attribute__((ext_vector_type(8))) short short8;
typedef __attribute__((ext_vector_type(4))) float f32x4;

union ABfrag { uint2 u2[2]; uint4 u4; short8 s8; };

__device__ __forceinline__ float silu_f(float v) {
    return v * __builtin_amdgcn_rcpf(1.0f + __expf(-v));
}
// cheap bf16 pair pack (round-half-up): 2 adds + 1 v_perm
__device__ __forceinline__ u32 pk2(float lo, float hi) {
    return __builtin_amdgcn_perm(__float_as_uint(hi) + 0x8000u,
                                 __float_as_uint(lo) + 0x8000u, 0x07060302u);
}
__device__ __forceinline__ float bff(u32 h) { return __uint_as_float(h << 16); }

// ---------------- embedding: h64 = h @ emb_w + emb_b  (N x 16 -> N x 64)
__global__ __launch_bounds__(256, 4) void k_embed(const float* __restrict__ h,
        const float* __restrict__ w, const float* __restrict__ b,
        float* __restrict__ h64) {
    int n = blockIdx.x * 256 + threadIdx.x;
    if (n >= NN) return;
    const float4* h4 = (const float4*)(h + (long)n * 16);
    float in[16];
    #pragma unroll
    for (int c = 0; c < 4; ++c) {
        float4 v = h4[c];
        in[4*c+0] = v.x; in[4*c+1] = v.y; in[4*c+2] = v.z; in[4*c+3] = v.w;
    }
    float acc[64];
    #pragma unroll
    for (int j = 0; j < 64; ++j) acc[j] = b[j];
    #pragma unroll
    for (int k = 0; k < 16; ++k) {
        #pragma unroll
        for (int j = 0; j < 64; ++j) acc[j] = fmaf(in[k], w[k*64 + j], acc[j]);
    }
    float4* o4 = (float4*)(h64 + (long)n * 64);
    #pragma unroll
    for (int c = 0; c < 16; ++c)
        o4[c] = make_float4(acc[4*c+0], acc[4*c+1], acc[4*c+2], acc[4*c+3]);
}

// ---------------- CSR-order build ----------------
__global__ __launch_bounds__(256, 4) void k_hist(const int* __restrict__ row,
        int* __restrict__ deg) {
    int e = blockIdx.x * 256 + threadIdx.x;
    if (e < NE) atomicAdd(&deg[row[e]], 1);
}

__global__ __launch_bounds__(256, 4) void k_scanA(const int* __restrict__ deg,
        int* __restrict__ bsum) {
    int t = threadIdx.x, i = blockIdx.x * 256 + t;
    int v = (i < NN) ? deg[i] : 0;
    #pragma unroll
    for (int d = 1; d < 64; d <<= 1) v += __shfl_xor(v, d);
    __shared__ int ws[4];
    if ((t & 63) == 0) ws[t >> 6] = v;
    __syncthreads();
    if (t == 0) bsum[blockIdx.x] = ws[0] + ws[1] + ws[2] + ws[3];
}

__global__ __launch_bounds__(256) void k_scanB(const int* __restrict__ bsum,
        int* __restrict__ bpre) {
    __shared__ int s[256];
    int t = threadIdx.x;
    int v = (t < NB) ? bsum[t] : 0;
    s[t] = v;
    __syncthreads();
    #pragma unroll
    for (int d = 1; d < 256; d <<= 1) {
        int u = (t >= d) ? s[t - d] : 0;
        __syncthreads();
        s[t] += u;
        __syncthreads();
    }
    if (t < NB) bpre[t] = s[t] - v;
}

__global__ __launch_bounds__(256, 4) void k_scanC(const int* __restrict__ deg,
        const int* __restrict__ bpre, int* __restrict__ base) {
    int t = threadIdx.x, i = blockIdx.x * 256 + t;
    int lane = t & 63, w = t >> 6;
    int v = (i < NN) ? deg[i] : 0;
    int x = v;
    #pragma unroll
    for (int d = 1; d < 64; d <<= 1) {
        int u = __shfl_up(x, d);
        if (lane >= d) x += u;
    }
    __shared__ int wsum[4];
    if (lane == 63) wsum[w] = x;
    __syncthreads();
    int off = bpre[blockIdx.x];
    #pragma unroll
    for (int ww = 0; ww < 3; ++ww) if (ww < w) off += wsum[ww];
    if (i < NN) base[i] = off + x - v;
}

// scatter into row-sorted edge records {r, c, d0, rad}
__global__ __launch_bounds__(256, 4) void k_scatter(const int* __restrict__ row,
        const int* __restrict__ col, int* __restrict__ base,
        int4* __restrict__ erec) {
    int e = blockIdx.x * 256 + threadIdx.x;
    if (e >= NE) return;
    int r = row[e];
    int p = atomicAdd(&base[r], 1);
    erec[p] = make_int4(r, col[e], 0, 0);
}

// per-edge squared distance -> record fields (mode 0: d0 & rad; mode 1: rad only)
__global__ __launch_bounds__(256, 4) void k_radial(const float* __restrict__ x,
        int4* __restrict__ erec, int mode) {
    int e = blockIdx.x * 256 + threadIdx.x;
    if (e >= NE) return;
    int4 rec = erec[e];
    int r = rec.x, c = rec.y;
    float dx = x[r*3+0] - x[c*3+0];
    float dy = x[r*3+1] - x[c*3+1];
    float dz = x[r*3+2] - x[c*3+2];
    float rad = dx*dx + dy*dy + dz*dz;
    rec.w = __float_as_int(rad);
    if (mode == 0) rec.z = rec.w;
    erec[e] = rec;
}

// ---------------- weight -> bf16 B-fragment tables (RNE, one-time)
__device__ __forceinline__ u32 bfr_rne(float x) {
    u32 u = __float_as_uint(x);
    u += 0x7fffu + ((u >> 16) & 1u);
    return u >> 16;
}
__global__ __launch_bounds__(256, 4) void k_wconv(const float* __restrict__ e_w2,
        const float* __restrict__ q_w2, const float* __restrict__ n_w1,
        const float* __restrict__ n_w2, const float* __restrict__ e_w1,
        const float* __restrict__ q_w1, u16* __restrict__ wf) {
    int t = blockIdx.x * 256 + threadIdx.x;
    if (t >= 122880) return;
    int j, lane, n, s, k, col;
    if (t < 24576) {
        int L = t >> 12, v = t & 4095;
        j = v & 7; lane = (v >> 3) & 63; int ns = v >> 9; n = ns >> 1; s = ns & 1;
        k = 8*(lane >> 4) + j + 32*s;
        col = 16*n + (lane & 15);
        const float* src = (L < 4) ? e_w2 + (size_t)L*4096 : q_w2 + (size_t)(L-4)*4096;
        wf[t] = (u16)bfr_rne(src[k*64 + col]);
    } else if (t < 57344) {
        int u = t - 24576; int L = u >> 13, v = u & 8191;
        j = v & 7; lane = (v >> 3) & 63; int ns = v >> 9; n = ns >> 2; s = ns & 3;
        k = 8*(lane >> 4) + j + 32*s;
        col = 16*n + (lane & 15);
        wf[t] = (u16)bfr_rne(n_w1[(size_t)L*8192 + k*64 + col]);
    } else if (t < 73728) {
        int u = t - 57344; int L = u >> 12, v = u & 4095;
        j = v & 7; lane = (v >> 3) & 63; int ns = v >> 9; n = ns >> 1; s = ns & 1;
        k = 8*(lane >> 4) + j + 32*s;
        col = 16*n + (lane & 15);
        wf[t] = (u16)bfr_rne(n_w2[(size_t)L*4096 + k*64 + col]);
    } else {
        int u = t - 73728;
        int L = u >> 13;
        int v = u & 8191;
        int m = v >> 12;
        int v2 = v & 4095;
        j = v2 & 7; lane = (v2 >> 3) & 63; int ns = v2 >> 9; n = ns >> 1; s = ns & 1;
        k = 8*(lane >> 4) + j + 32*s;
        col = 16*n + (lane & 15);
        const float* src = (L < 4) ? e_w1 + (size_t)L*130*64
                                   : q_w1 + (size_t)(L-4)*130*64;
        wf[t] = (u16)bfr_rne(src[(size_t)(m*64 + k)*64 + col]);
    }
}

// ---------------- standalone P/Q via MFMA (layer l0 only)
__global__ __launch_bounds__(256, 4) void k_pq(const float* __restrict__ h64,
        const u16* __restrict__ wpf, const float* __restrict__ b1,
        u32* __restrict__ Pb, u32* __restrict__ Qb) {
    __shared__ u16 A[64*64];
    __shared__ u16 XP[64*68], XQ[64*68];
    int t = threadIdx.x, w = t >> 6, lane = t & 63;
    int nb0 = blockIdx.x * 64;
    #pragma unroll
    for (int i = 0; i < 4; ++i) {
        int idx = i*256 + t;
        int r = idx >> 4, c = idx & 15;
        int n = nb0 + r;
        float4 v = make_float4(0.f, 0.f, 0.f, 0.f);
        if (n < NN) v = ((const float4*)(h64 + (size_t)n*64))[c];
        uint2 pk = make_uint2(pk2(v.x, v.y), pk2(v.z, v.w));
        *(uint2*)((char*)A + r*128 + ((8*c) ^ ((r & 15) << 3))) = pk;
    }
    __syncthreads();
    int r0 = lane & 15, g = lane >> 4;
    ABfrag bp[2], bq[2];
    #pragma unroll
    for (int s = 0; s < 2; ++s) {
        bp[s].u4 = *(const uint4*)(wpf + ((size_t)(w*2 + s)*64 + lane)*8);
        bq[s].u4 = *(const uint4*)(wpf + 4096 + ((size_t)(w*2 + s)*64 + lane)*8);
    }
    f32x4 aP[4], aQ[4];
    #pragma unroll
    for (int t4 = 0; t4 < 4; ++t4) {
        aP[t4] = (f32x4){0.f, 0.f, 0.f, 0.f};
        aQ[t4] = (f32x4){0.f, 0.f, 0.f, 0.f};
    }
    #pragma unroll
    for (int t4 = 0; t4 < 4; ++t4) {
        #pragma unroll
        for (int s = 0; s < 2; ++s) {
            int boff = 16*g + 64*s;
            ABfrag af;
            af.u2[0] = *(uint2*)((char*)A + (16*t4 + r0)*128 + ( boff      ^ (r0 << 3)));
            af.u2[1] = *(uint2*)((char*)A + (16*t4 + r0)*128 + ((boff + 8) ^ (r0 << 3)));
            aP[t4] = __builtin_amdgcn_mfma_f32_16x16x32_bf16(af.s8, bp[s].s8, aP[t4], 0, 0, 0);
            aQ[t4] = __builtin_amdgcn_mfma_f32_16x16x32_bf16(af.s8, bq[s].s8, aQ[t4], 0, 0, 0);
        }
    }
    float bv = b1[16*w + r0];
    #pragma unroll
    for (int t4 = 0; t4 < 4; ++t4)
        #pragma unroll
        for (int q = 0; q < 4; ++q) {
            int rw = 16*t4 + 4*g + q;
            XP[rw*68 + 16*w + r0] = (u16)(pk2(aP[t4][q] + bv, 0.f) & 0xffffu);
            XQ[rw*68 + 16*w + r0] = (u16)(pk2(aQ[t4][q], 0.f) & 0xffffu);
        }
    __syncthreads();
    int node = t >> 2, part = t & 3;
    if (nb0 + node < NN) {
        const u32* XPw = (const u32*)XP;
        const u32* XQw = (const u32*)XQ;
        u32 b[8];
        #pragma unroll
        for (int j = 0; j < 8; ++j) b[j] = XPw[node*34 + 8*part + j];
        uint4* dp = (uint4*)(Pb + (size_t)(nb0 + node)*32 + part*8);
        dp[0] = make_uint4(b[0], b[1], b[2], b[3]);
        dp[1] = make_uint4(b[4], b[5], b[6], b[7]);
        #pragma unroll
        for (int j = 0; j < 8; ++j) b[j] = XQw[node*34 + 8*part + j];
        uint4* dq = (uint4*)(Qb + (size_t)(nb0 + node)*32 + part*8);
        dq[0] = make_uint4(b[0], b[1], b[2], b[3]);
        dq[1] = make_uint4(b[4], b[5], b[6], b[7]);
    }
}

// ---------------- edge MLP: reg-direct A-fragments, edge records, M in LDS
__global__ __launch_bounds__(256, 4) void k_edge(
        const u32* __restrict__ Pb, const u32* __restrict__ Qb,
        const int4* __restrict__ erec,
        const float* __restrict__ w1t, const u16* __restrict__ w2f,
        const float* __restrict__ b2, float* __restrict__ agg) {
    __shared__ u16 M_lds[4][64*66];   // per-wave [64 feat][66 edge] bf16
    int tid = threadIdx.x;
    int w = tid >> 6, lane = tid & 63;
    int ebase = blockIdx.x * 256 + w * 64;
    u16* Mw = M_lds[w];
    int r0 = lane & 15, g = lane >> 4;
    float wa[16], wb[16];
    *(float4*)&wa[0]  = *(const float4*)(w1t + 8*g);
    *(float4*)&wa[4]  = *(const float4*)(w1t + 8*g + 4);
    *(float4*)&wa[8]  = *(const float4*)(w1t + 32 + 8*g);
    *(float4*)&wa[12] = *(const float4*)(w1t + 36 + 8*g);
    *(float4*)&wb[0]  = *(const float4*)(w1t + 64 + 8*g);
    *(float4*)&wb[4]  = *(const float4*)(w1t + 68 + 8*g);
    *(float4*)&wb[8]  = *(const float4*)(w1t + 96 + 8*g);
    *(float4*)&wb[12] = *(const float4*)(w1t + 100 + 8*g);
    ABfrag bf[4][2];
    #pragma unroll
    for (int n = 0; n < 4; ++n)
        #pragma unroll
        for (int s = 0; s < 2; ++s)
            bf[n][s].u4 = *(const uint4*)(w2f + ((n*2 + s)*64 + lane)*8);
    float b2v[4];
    #pragma unroll
    for (int n = 0; n < 4; ++n) b2v[n] = b2[16*n + r0];
    #pragma unroll
    for (int t = 0; t < 4; ++t) {
        int et = ebase + 16*t + r0;
        int4 rec = erec[et];
        int r = rec.x, c = rec.y;
        float d0 = __int_as_float(rec.z), rad = __int_as_float(rec.w);
        uint4 pA = *(const uint4*)(Pb + (size_t)r*32 + 4*g);
        uint4 pB = *(const uint4*)(Pb + (size_t)r*32 + 16 + 4*g);
        uint4 qA = *(const uint4*)(Qb + (size_t)c*32 + 4*g);
        uint4 qB = *(const uint4*)(Qb + (size_t)c*32 + 16 + 4*g);
        u32 pu[8] = {pA.x, pA.y, pA.z, pA.w, pB.x, pB.y, pB.z, pB.w};
        u32 qu[8] = {qA.x, qA.y, qA.z, qA.w, qB.x, qB.y, qB.z, qB.w};
        u32 pk[8];
        #pragma unroll
        for (int i = 0; i < 8; ++i) {
            int kb = (i >> 2) * 8 + (i & 3) * 2;
            float pl = bff(pu[i] & 0xffffu), ph = bff(pu[i] >> 16);
            float ql = bff(qu[i] & 0xffffu), qh = bff(qu[i] >> 16);
            float h0 = silu_f(pl + ql + rad*wa[kb]   + d0*wb[kb]);
            float h1 = silu_f(ph + qh + rad*wa[kb+1] + d0*wb[kb+1]);
            pk[i] = pk2(h0, h1);
        }
        ABfrag af0, af1;
        af0.u4 = make_uint4(pk[0], pk[1], pk[2], pk[3]);
        af1.u4 = make_uint4(pk[4], pk[5], pk[6], pk[7]);
        f32x4 acc[4];
        #pragma unroll
        for (int n = 0; n < 4; ++n) acc[n] = (f32x4){0.f, 0.f, 0.f, 0.f};
        #pragma unroll
        for (int n = 0; n < 4; ++n) {
            acc[n] = __builtin_amdgcn_mfma_f32_16x16x32_bf16(af0.s8, bf[n][0].s8, acc[n], 0, 0, 0);
            acc[n] = __builtin_amdgcn_mfma_f32_16x16x32_bf16(af1.s8, bf[n][1].s8, acc[n], 0, 0, 0);
        }
        #pragma unroll
        for (int n = 0; n < 4; ++n) {
            f32x4 z = acc[n];
            u32 m0 = pk2(silu_f(z[0] + b2v[n]), silu_f(z[1] + b2v[n]));
            u32 m1 = pk2(silu_f(z[2] + b2v[n]), silu_f(z[3] + b2v[n]));
            *(uint2*)((char*)Mw + (16*n + r0)*132 + 32*t + 8*g) = make_uint2(m0, m1);
        }
    }
    // aggregation: per-wave LDS, within-wave in-order DS -> no barrier
    int rl = *(const int*)(erec + ebase + lane);
    int rnext = __shfl_down(rl, 1);
    unsigned long long tm = __ballot((lane == 63) || (rnext != rl));
    float racc = 0.0f;
    #pragma unroll
    for (int ch = 0; ch < 16; ++ch) {
        uint2 mm = *(uint2*)((char*)Mw + lane*132 + 8*ch);
        u32 mw[2] = {mm.x, mm.y};
        #pragma unroll
        for (int q = 0; q < 4; ++q) {
            int ee = 4*ch + q;
            racc += bff((mw[q >> 1] >> ((q & 1) * 16)) & 0xffffu);
            if ((tm >> ee) & 1ull) {
                int rr = __builtin_amdgcn_readlane(rl, ee);
                atomicAdd(&agg[(size_t)rr*64 + lane], racc);
                racc = 0.0f;
            }
        }
    }
}

// ---------------- fused node MLP + next-layer P/Q (dual-output capable)
__global__ __launch_bounds__(256, 3) void k_node_pq(float* __restrict__ h64,
        float* __restrict__ agg,
        const u16* __restrict__ w1f, const float* __restrict__ b1,
        const u16* __restrict__ w2f, const float* __restrict__ b2,
        const u16* __restrict__ wpf, const float* __restrict__ b1pq,
        u32* __restrict__ Pb, u32* __restrict__ Qb,
        const u16* __restrict__ wpf2, const float* __restrict__ b1pq2,
        u32* __restrict__ Pb2, u32* __restrict__ Qb2, int has2) {
    __shared__ u16 S[16512];
    u16* A0 = S;
    u16* A1 = S + 4096;
    u16* H  = S + 8192;
    u16* D  = S + 12288;
    u16* An = S;
    u16* XPh = S + 4096;
    u16* XQh = S + 8448;
    int t = threadIdx.x, w = t >> 6, lane = t & 63;
    int nb0 = blockIdx.x * 64;
    #pragma unroll
    for (int i = 0; i < 8; ++i) {
        int idx = i*256 + t;
        int r = idx >> 5, c = idx & 31;
        int n = nb0 + r;
        float4 v = make_float4(0.f, 0.f, 0.f, 0.f);
        if (n < NN) {
            if (c < 16) v = ((const float4*)(h64 + (size_t)n*64))[c];
            else {
                float4 a = ((const float4*)(agg + (size_t)n*64))[c-16];
                ((float4*)(agg + (size_t)n*64))[c-16] = make_float4(0.f,0.f,0.f,0.f);
                v = make_float4(a.x*0.01f, a.y*0.01f, a.z*0.01f, a.w*0.01f);
            }
        }
        uint2 pk = make_uint2(pk2(v.x, v.y), pk2(v.z, v.w));
        u16* dst = (c < 16) ? A0 : A1;
        int cc = c & 15;
        *(uint2*)((char*)dst + r*128 + ((8*cc) ^ ((r & 15) << 3))) = pk;
    }
    __syncthreads();
    int r0 = lane & 15, g = lane >> 4;
    ABfrag bf1[4];
    #pragma unroll
    for (int s = 0; s < 4; ++s)
        bf1[s].u4 = *(const uint4*)(w1f + ((size_t)(w*4 + s)*64 + lane)*8);
    f32x4 acc[4];
    #pragma unroll
    for (int t4 = 0; t4 < 4; ++t4) acc[t4] = (f32x4){0.f, 0.f, 0.f, 0.f};
    #pragma unroll
    for (int t4 = 0; t4 < 4; ++t4) {
        #pragma unroll
        for (int s = 0; s < 4; ++s) {
            const u16* Ah = (s < 2) ? A0 : A1;
            int boff = 16*g + 64*(s & 1);
            ABfrag af;
            af.u2[0] = *(uint2*)((char*)Ah + (16*t4 + r0)*128 + ( boff      ^ (r0 << 3)));
            af.u2[1] = *(uint2*)((char*)Ah + (16*t4 + r0)*128 + ((boff + 8) ^ (r0 << 3)));
            acc[t4] = __builtin_amdgcn_mfma_f32_16x16x32_bf16(
                af.s8, bf1[s].s8, acc[t4], 0, 0, 0);
        }
    }
    float b1v = b1[16*w + r0];
    #pragma unroll
    for (int t4 = 0; t4 < 4; ++t4)
        #pragma unroll
        for (int q = 0; q < 4; ++q) {
            int rw = 16*t4 + 4*g + q;
            u16 hv = (u16)(pk2(silu_f(acc[t4][q] + b1v), 0.f) & 0xffffu);
            *(u16*)((char*)H + rw*128 + ((2*(16*w + r0)) ^ ((rw & 15) << 3))) = hv;
        }
    __syncthreads();
    ABfrag bf2[2];
    #pragma unroll
    for (int s = 0; s < 2; ++s)
        bf2[s].u4 = *(const uint4*)(w2f + ((size_t)(w*2 + s)*64 + lane)*8);
    f32x4 acc2[4];
    #pragma unroll
    for (int t4 = 0; t4 < 4; ++t4) acc2[t4] = (f32x4){0.f, 0.f, 0.f, 0.f};
    #pragma unroll
    for (int t4 = 0; t4 < 4; ++t4) {
        #pragma unroll
        for (int s = 0; s < 2; ++s) {
            int boff = 16*g + 64*s;
            ABfrag af;
            af.u2[0] = *(uint2*)((char*)H + (16*t4 + r0)*128 + ( boff      ^ (r0 << 3)));
            af.u2[1] = *(uint2*)((char*)H + (16*t4 + r0)*128 + ((boff + 8) ^ (r0 << 3)));
            acc2[t4] = __builtin_amdgcn_mfma_f32_16x16x32_bf16(
                af.s8, bf2[s].s8, acc2[t4], 0, 0, 0);
        }
    }
    float b2v = b2[16*w + r0];
    #pragma unroll
    for (int t4 = 0; t4 < 4; ++t4)
        #pragma unroll
        for (int q = 0; q < 4; ++q) {
            int rw = 16*t4 + 4*g + q;
            D[rw*66 + 16*w + r0] = (u16)(pk2(acc2[t4][q] + b2v, 0.f) & 0xffffu);
        }
    __syncthreads();
    // residual RMW (coalesced) + build new-h A-tile
    #pragma unroll
    for (int i = 0; i < 4; ++i) {
        int idx = i*256 + t;
        int rr = idx >> 4, cc = idx & 15;
        int n = nb0 + rr;
        float4 v = make_float4(0.f, 0.f, 0.f, 0.f);
        if (n < NN) {
            v = ((const float4*)(h64 + (size_t)n*64))[cc];
            v.x += bff(D[rr*66 + 4*cc + 0]);
            v.y += bff(D[rr*66 + 4*cc + 1]);
            v.z += bff(D[rr*66 + 4*cc + 2]);
            v.w += bff(D[rr*66 + 4*cc + 3]);
            ((float4*)(h64 + (size_t)n*64))[cc] = v;
        }
        uint2 pk = make_uint2(pk2(v.x, v.y), pk2(v.z, v.w));
        *(uint2*)((char*)An + rr*128 + ((8*cc) ^ ((rr & 15) << 3))) = pk;
    }
    __syncthreads();
    // ---- P/Q output set 1
    for (int set = 0; set < 1 + (has2 ? 1 : 0); ++set) {
        const u16* wp = set ? wpf2 : wpf;
        const float* bb = set ? b1pq2 : b1pq;
        u32* Pd = set ? Pb2 : Pb;
        u32* Qd = set ? Qb2 : Qb;
        ABfrag bp[2], bq[2];
        #pragma unroll
        for (int s = 0; s < 2; ++s) {
            bp[s].u4 = *(const uint4*)(wp + ((size_t)(w*2 + s)*64 + lane)*8);
            bq[s].u4 = *(const uint4*)(wp + 4096 + ((size_t)(w*2 + s)*64 + lane)*8);
        }
        f32x4 aP[4], aQ[4];
        #pragma unroll
        for (int t4 = 0; t4 < 4; ++t4) {
            aP[t4] = (f32x4){0.f, 0.f, 0.f, 0.f};
            aQ[t4] = (f32x4){0.f, 0.f, 0.f, 0.f};
        }
        #pragma unroll
        for (int t4 = 0; t4 < 4; ++t4) {
            #pragma unroll
            for (int s = 0; s < 2; ++s) {
                int boff = 16*g + 64*s;
                ABfrag af;
                af.u2[0] = *(uint2*)((char*)An + (16*t4 + r0)*128 + ( boff      ^ (r0 << 3)));
                af.u2[1] = *(uint2*)((char*)An + (16*t4 + r0)*128 + ((boff + 8) ^ (r0 << 3)));
                aP[t4] = __builtin_amdgcn_mfma_f32_16x16x32_bf16(af.s8, bp[s].s8, aP[t4], 0, 0, 0);
                aQ[t4] = __builtin_amdgcn_mfma_f32_16x16x32_bf16(af.s8, bq[s].s8, aQ[t4], 0, 0, 0);
            }
        }
        float bv = bb[16*w + r0];
        #pragma unroll
        for (int t4 = 0; t4 < 4; ++t4)
            #pragma unroll
            for (int q = 0; q < 4; ++q) {
                int rw = 16*t4 + 4*g + q;
                XPh[rw*68 + 16*w + r0] = (u16)(pk2(aP[t4][q] + bv, 0.f) & 0xffffu);
                XQh[rw*68 + 16*w + r0] = (u16)(pk2(aQ[t4][q], 0.f) & 0xffffu);
            }
        __syncthreads();
        int node = t >> 2, part = t & 3;
        if (nb0 + node < NN) {
            const u32* XPw = (const u32*)XPh;
            const u32* XQw = (const u32*)XQh;
            u32 b[8];
            #pragma unroll
            for (int j = 0; j < 8; ++j) b[j] = XPw[node*34 + 8*part + j];
            uint4* dp = (uint4*)(Pd + (size_t)(nb0 + node)*32 + part*8);
            dp[0] = make_uint4(b[0], b[1], b[2], b[3]);
            dp[1] = make_uint4(b[4], b[5], b[6], b[7]);
            #pragma unroll
            for (int j = 0; j < 8; ++j) b[j] = XQw[node*34 + 8*part + j];
            uint4* dq = (uint4*)(Qd + (size_t)(nb0 + node)*32 + part*8);
            dq[0] = make_uint4(b[0], b[1], b[2], b[3]);
            dq[1] = make_uint4(b[4], b[5], b[6], b[7]);
        }
        __syncthreads();   // XPh/XQh reads complete before next set overwrites
    }
}

// ---------------- coordinate update: reg-direct A, edge records, tiny LDS
__global__ __launch_bounds__(256, 4) void k_coord(
        const u32* __restrict__ Pb, const u32* __restrict__ Qb,
        const int4* __restrict__ erec,
        const float* __restrict__ w1t, const u16* __restrict__ w2f,
        const float* __restrict__ b2, const float* __restrict__ w3,
        const float* __restrict__ x_old, float* __restrict__ x_new) {
    __shared__ float PHL[4][64];
    int tid = threadIdx.x;
    int w = tid >> 6, lane = tid & 63;
    int ebase = blockIdx.x * 256 + w * 64;
    int r0 = lane & 15, g = lane >> 4;
    float wa[16], wb[16];
    *(float4*)&wa[0]  = *(const float4*)(w1t + 8*g);
    *(float4*)&wa[4]  = *(const float4*)(w1t + 8*g + 4);
    *(float4*)&wa[8]  = *(const float4*)(w1t + 32 + 8*g);
    *(float4*)&wa[12] = *(const float4*)(w1t + 36 + 8*g);
    *(float4*)&wb[0]  = *(const float4*)(w1t + 64 + 8*g);
    *(float4*)&wb[4]  = *(const float4*)(w1t + 68 + 8*g);
    *(float4*)&wb[8]  = *(const float4*)(w1t + 96 + 8*g);
    *(float4*)&wb[12] = *(const float4*)(w1t + 100 + 8*g);
    ABfrag bf[4][2];
    #pragma unroll
    for (int n = 0; n < 4; ++n)
        #pragma unroll
        for (int s = 0; s < 2; ++s)
            bf[n][s].u4 = *(const uint4*)(w2f + ((n*2 + s)*64 + lane)*8);
    float w3v[4], b2v[4];
    #pragma unroll
    for (int n = 0; n < 4; ++n) { w3v[n] = w3[16*n + r0]; b2v[n] = b2[16*n + r0]; }
    float ph[16];
    #pragma unroll
    for (int t = 0; t < 4; ++t) {
        int et = ebase + 16*t + r0;
        int4 rec = erec[et];
        int r = rec.x, c = rec.y;
        float d0 = __int_as_float(rec.z), rad = __int_as_float(rec.w);
        uint4 pA = *(const uint4*)(Pb + (size_t)r*32 + 4*g);
        uint4 pB = *(const uint4*)(Pb + (size_t)r*32 + 16 + 4*g);
        uint4 qA = *(const uint4*)(Qb + (size_t)c*32 + 4*g);
        uint4 qB = *(const uint4*)(Qb + (size_t)c*32 + 16 + 4*g);
        u32 pu[8] = {pA.x, pA.y, pA.z, pA.w, pB.x, pB.y, pB.z, pB.w};
        u32 qu[8] = {qA.x, qA.y, qA.z, qA.w, qB.x, qB.y, qB.z, qB.w};
        u32 pk[8];
        #pragma unroll
        for (int i = 0; i < 8; ++i) {
            int kb = (i >> 2) * 8 + (i & 3) * 2;
            float pl = bff(pu[i] & 0xffffu), phh = bff(pu[i] >> 16);
            float ql = bff(qu[i] & 0xffffu), qh = bff(qu[i] >> 16);
            float h0 = silu_f(pl + ql + rad*wa[kb]   + d0*wb[kb]);
            float h1 = silu_f(phh + qh + rad*wa[kb+1] + d0*wb[kb+1]);
            pk[i] = pk2(h0, h1);
        }
        ABfrag af0, af1;
        af0.u4 = make_uint4(pk[0], pk[1], pk[2], pk[3]);
        af1.u4 = make_uint4(pk[4], pk[5], pk[6], pk[7]);
        f32x4 acc[4];
        #pragma unroll
        for (int n = 0; n < 4; ++n) acc[n] = (f32x4){0.f, 0.f, 0.f, 0.f};
        #pragma unroll
        for (int n = 0; n < 4; ++n) {
            acc[n] = __builtin_amdgcn_mfma_f32_16x16x32_bf16(af0.s8, bf[n][0].s8, acc[n], 0, 0, 0);
            acc[n] = __builtin_amdgcn_mfma_f32_16x16x32_bf16(af1.s8, bf[n][1].s8, acc[n], 0, 0, 0);
        }
        #pragma unroll
        for (int q = 0; q < 4; ++q) {
            float s = 0.f;
            #pragma unroll
            for (int n = 0; n < 4; ++n)
                s = fmaf(silu_f(acc[n][q] + b2v[n]), w3v[n], s);
            ph[t*4 + q] = s;
        }
    }
    #pragma unroll
    for (int d = 1; d < 16; d <<= 1)
        #pragma unroll
        for (int i = 0; i < 16; ++i) ph[i] += __shfl_xor(ph[i], d);
    if (r0 == 0) {
        #pragma unroll
        for (int t = 0; t < 4; ++t)
            #pragma unroll
            for (int q = 0; q < 4; ++q)
                PHL[w][16*t + 4*g + q] = ph[t*4 + q];
    }
    int e = ebase + lane;
    float phi = PHL[w][lane] * 0.01f;
    int4 rec = erec[e];
    int r = rec.x, c = rec.y;
    float rad = __int_as_float(rec.w);
    float dx = x_old[r*3+0] - x_old[c*3+0];
    float dy = x_old[r*3+1] - x_old[c*3+1];
    float dz = x_old[r*3+2] - x_old[c*3+2];
    float inv = phi / (sqrtf(rad + 1e-8f) + 1.0f);
    float tx = dx * inv, ty = dy * inv, tz = dz * inv;
    int rprev = __shfl_up(r, 1);
    bool head = (lane == 0) || (rprev != r);
    unsigned long long hm = __ballot(head);
    int runid = __popcll(hm & ((2ull << lane) - 1ull));
    #pragma unroll
    for (int d = 1; d < 64; d <<= 1) {
        float ox = __shfl_up(tx, d);
        float oy = __shfl_up(ty, d);
        float oz = __shfl_up(tz, d);
        int orid = __shfl_up(runid, d);
        if (lane >= d && orid == runid) { tx += ox; ty += oy; tz += oz; }
    }
    int rid_next = __shfl_down(runid, 1);
    bool tail = (lane == 63) || (rid_next != runid);
    if (tail) {
        atomicAdd(&x_new[r*3+0], tx);
        atomicAdd(&x_new[r*3+1], ty);
        atomicAdd(&x_new[r*3+2], tz);
    }
}

// ---------------- output projection
__global__ __launch_bounds__(256, 4) void k_out(const float* __restrict__ h64,
        const float* __restrict__ w, const float* __restrict__ b,
        float* __restrict__ out) {
    int n = blockIdx.x * 256 + threadIdx.x;
    if (n >= NN) return;
    float acc[16];
    #pragma unroll
    for (int j = 0; j < 16; ++j) acc[j] = b[j];
    const float4* h4 = (const float4*)(h64 + (long)n*64);
    #pragma unroll
    for (int c = 0; c < 16; ++c) {
        float4 v = h4[c];
        float vv[4] = {v.x, v.y, v.z, v.w};
        #pragma unroll
        for (int t = 0; t < 4; ++t) {
            #pragma unroll
            for (int j = 0; j < 16; ++j)
                acc[j] = fmaf(vv[t], w[(4*c+t)*16 + j], acc[j]);
        }
    }
    float4* o4 = (float4*)(out + (long)n*16);
    #pragma unroll
    for (int cq = 0; cq < 4; ++cq)
        o4[cq] = make_float4(acc[4*cq+0],acc[4*cq+1],acc[4*cq+2],acc[4*cq+3]);
}

extern "C" void kernel_launch(void* const* d_in, const int* in_sizes, int n_in,
                              void* d_out, int out_size, void* d_ws, size_t ws_size,
                              hipStream_t stream) {
    const float* h_in  = (const float*)d_in[0];
    const float* x_in  = (const float*)d_in[1];
    const int*   row   = (const int*)d_in[2];
    const int*   col   = (const int*)d_in[3];
    const float* emb_w = (const float*)d_in[4];
    const float* emb_b = (const float*)d_in[5];
    const float* out_w = (const float*)d_in[6];
    const float* out_b = (const float*)d_in[7];
    const float* e_w1  = (const float*)d_in[8];
    const float* e_b1  = (const float*)d_in[9];
    const float* e_w2  = (const float*)d_in[10];
    const float* e_b2  = (const float*)d_in[11];
    const float* n_w1  = (const float*)d_in[12];
    const float* n_b1  = (const float*)d_in[13];
    const float* n_w2  = (const float*)d_in[14];
    const float* n_b2  = (const float*)d_in[15];
    const float* q_w1  = (const float*)d_in[16];
    const float* q_b1  = (const float*)d_in[17];
    const float* q_w2  = (const float*)d_in[18];
    const float* q_b2  = (const float*)d_in[19];
    const float* q_w3  = (const float*)d_in[20];

    const size_t WF_N = 122880;
    const size_t WF_BYTES = WF_N * sizeof(u16);
    size_t need = WF_BYTES + ((size_t)NN*64 + (size_t)NN*32*4 + (size_t)NN*64
                   + (size_t)NE*4 + (size_t)NN*3 + (size_t)NN*2 + 2048) * 4;
    if (ws_size < need) return;

    u16*   wf    = (u16*)d_ws;
    float* fb    = (float*)((char*)d_ws + WF_BYTES);
    float* h64   = fb;                                // NN*64 f32
    u32*   Pb    = (u32*)(h64 + (size_t)NN*64);       // NN*32
    u32*   Qb    = Pb  + (size_t)NN*32;
    u32*   Pb2   = Qb  + (size_t)NN*32;
    u32*   Qb2   = Pb2 + (size_t)NN*32;
    float* agg   = (float*)(Qb2 + (size_t)NN*32);     // NN*64 f32
    int4*  erec  = (int4*)(agg + (size_t)NN*64);      // NE records
    float* xA    = (float*)(erec + (size_t)NE);       // NN*3
    int*   deg   = (int*)(xA + (size_t)NN*3);         // NN
    int*   base  = deg  + (size_t)NN;                 // NN
    int*   bsum  = base + (size_t)NN;                 // NB
    int*   bpre  = bsum + 256;                        // NB

    float* out_h = (float*)d_out;
    float* out_x = out_h + (size_t)NN*16;

    dim3 th(256);
    dim3 nb((NN + 255)/256);
    dim3 eb(NE/256);
    dim3 t64b((NN + 63)/64);

    hipMemsetAsync(deg, 0, (size_t)NN*sizeof(int), stream);
    k_hist<<<eb, th, 0, stream>>>(row, deg);
    k_scanA<<<NB, th, 0, stream>>>(deg, bsum);
    k_scanB<<<1, th, 0, stream>>>(bsum, bpre);
    k_scanC<<<NB, th, 0, stream>>>(deg, bpre, base);
    k_scatter<<<eb, th, 0, stream>>>(row, col, base, erec);
    k_wconv<<<480, th, 0, stream>>>(e_w2, q_w2, n_w1, n_w2, e_w1, q_w1, wf);

    k_radial<<<eb, th, 0, stream>>>(x_in, erec, 0);
    k_embed<<<nb, th, 0, stream>>>(h_in, emb_w, emb_b, h64);
    hipMemsetAsync(agg, 0, (size_t)NN*64*sizeof(float), stream);   // once

    const u16* nw1f = wf + 24576;
    const u16* nw2f = wf + 57344;
    const u16* pqf  = wf + 73728;   // + L*8192, L: 0..3 edge, 4..5 coord

    // ---- block 0 ----
    k_pq<<<t64b, th, 0, stream>>>(h64, pqf, e_b1, Pb, Qb);              // l0
    k_edge<<<eb, th, 0, stream>>>(Pb, Qb, erec,
            e_w1 + 128*64, wf, e_b2, agg);                              // l0
    k_node_pq<<<t64b, th, 0, stream>>>(h64, agg,
            nw1f, n_b1, nw2f, n_b2,
            pqf + 8192, e_b1 + 64, Pb, Qb,                              // -> l1 P/Q
            nullptr, nullptr, nullptr, nullptr, 0);
    k_edge<<<eb, th, 0, stream>>>(Pb, Qb, erec,
            e_w1 + (size_t)1*130*64 + 128*64, wf + 4096, e_b2 + 64, agg); // l1
    k_node_pq<<<t64b, th, 0, stream>>>(h64, agg,
            nw1f + 8192, n_b1 + 64, nw2f + 4096, n_b2 + 64,
            pqf + (size_t)4*8192, q_b1, Pb, Qb,                         // -> coord b0
            pqf + (size_t)2*8192, e_b1 + 128, Pb2, Qb2, 1);             // -> l2 P/Q
    hipMemcpyAsync(xA, x_in, (size_t)NN*3*sizeof(float),
                   hipMemcpyDeviceToDevice, stream);
    k_coord<<<eb, th, 0, stream>>>(Pb, Qb, erec,
            q_w1 + 128*64, wf + (size_t)4*4096, q_b2, q_w3, x_in, xA);

    // ---- block 1 ----
    k_radial<<<eb, th, 0, stream>>>(xA, erec, 1);
    k_edge<<<eb, th, 0, stream>>>(Pb2, Qb2, erec,
            e_w1 + (size_t)2*130*64 + 128*64, wf + (size_t)2*4096,
            e_b2 + 128, agg);                                           // l2
    k_node_pq<<<t64b, th, 0, stream>>>(h64, agg,
            nw1f + (size_t)2*8192, n_b1 + 128, nw2f + (size_t)2*4096, n_b2 + 128,
            pqf + (size_t)3*8192, e_b1 + 192, Pb, Qb,                   // -> l3 P/Q
            nullptr, nullptr, nullptr, nullptr, 0);
    k_edge<<<eb, th, 0, stream>>>(Pb, Qb, erec,
            e_w1 + (size_t)3*130*64 + 128*64, wf + (size_t)3*4096,
            e_b2 + 192, agg);                                           // l3
    k_node_pq<<<t64b, th, 0, stream>>>(h64, agg,
            nw1f + (size_t)3*8192, n_b1 + 192, nw2f + (size_t)3*4096, n_b2 + 192,
            pqf + (size_t)5*8192, q_b1 + 64, Pb, Qb,                    // -> coord b1
            nullptr, nullptr, nullptr, nullptr, 0);
    hipMemcpyAsync(out_x, xA, (size_t)NN*3*sizeof(float),
                   hipMemcpyDeviceToDevice, stream);
    k_coord<<<eb, th, 0, stream>>>(Pb, Qb, erec,
            q_w1 + (size_t)1*130*64 + 128*64, wf + (size_t)5*4096,
            q_b2 + 64, q_w3 + 64, xA, out_x);

    k_out<<<nb, th, 0, stream>>>(h64, out_w, out_b, out_h);
}